// Round 1
// baseline (339.468 us; speedup 1.0000x reference)
//
#include <hip/hip_runtime.h>

typedef _Float16 f16;
typedef _Float16 f16x8 __attribute__((ext_vector_type(8)));
typedef float f32x4 __attribute__((ext_vector_type(4)));

#define B_TOT 16384
#define HID_  512
#define LAT_  16
#define STY_  64
#define ND_   8

#define BM 128
#define BN 128
#define BK 32
#define LDSP 40   // padded LDS row stride in f16 (80 B rows; 16B-aligned, 2-way banks = free)

// ---------------- prep kernels ----------------

__global__ void init_counts_k(int* counts, int* cursors) {
  int t = threadIdx.x;
  if (t < ND_) { counts[t] = 0; cursors[t] = 0; }
}

__global__ void cast_x_k(const float* __restrict__ x, f16* __restrict__ x16) {
  int i = blockIdx.x * blockDim.x + threadIdx.x;  // over B_TOT*32
  int b = i >> 5, k = i & 31;
  x16[i] = (k < LAT_) ? (f16)x[b * LAT_ + k] : (f16)0.f;
}

// in: f32 [Kin][Nin] (+batch), out: f16 [Npad][Kpad] (+batch), zero padded.
__global__ void transpose_cast_k(const float* __restrict__ in, f16* __restrict__ out,
                                 int Kin, int Nin, int Kpad, int Npad,
                                 long isb, long osb) {
  __shared__ float tile[32][33];
  const float* ip = in + (long)blockIdx.z * isb;
  f16* op = out + (long)blockIdx.z * osb;
  int k0 = blockIdx.y * 32, n0 = blockIdx.x * 32;
  int tx = threadIdx.x, ty = threadIdx.y;  // 32 x 8
  #pragma unroll
  for (int i = 0; i < 32; i += 8) {
    int k = k0 + ty + i, n = n0 + tx;
    tile[ty + i][tx] = (k < Kin && n < Nin) ? ip[(long)k * Nin + n] : 0.f;
  }
  __syncthreads();
  #pragma unroll
  for (int i = 0; i < 32; i += 8) {
    int n = n0 + ty + i, k = k0 + tx;
    if (n < Npad && k < Kpad) op[(long)n * Kpad + k] = (f16)tile[tx][ty + i];
  }
}

__global__ void count_k(const int* __restrict__ y, int* counts) {
  int i = blockIdx.x * blockDim.x + threadIdx.x;
  if (i < B_TOT) atomicAdd(&counts[y[i]], 1);
}

__global__ void scan_k(const int* __restrict__ counts, int* offsets, int* cursors) {
  if (threadIdx.x == 0) {
    int s = 0;
    for (int d = 0; d < ND_; d++) { offsets[d] = s; cursors[d] = s; s += counts[d]; }
    offsets[ND_] = s;
  }
}

__global__ void scatter_k(const int* __restrict__ y, int* cursors, int* __restrict__ perm) {
  int i = blockIdx.x * blockDim.x + threadIdx.x;
  if (i < B_TOT) {
    int pos = atomicAdd(&cursors[y[i]], 1);
    perm[pos] = i;
  }
}

// ---------------- GEMM ----------------
// C[M,N] = act(A[M,K] @ W[K,N] + bias) ; W passed pre-transposed f16 [N][Ktot].
// MODE 0: trunk         — rows = blockIdx.y*BM.., fp16 relu out
// MODE 1: expert first  — per-domain tiles, A rows gathered via perm, fp16 relu out at slots
// MODE 2: expert mid    — per-domain tiles, contiguous slots in/out, fp16 relu out
// MODE 3: expert last   — per-domain tiles, scatter f32 out via perm, no relu, N=64 mask
template<int MODE>
__global__ __launch_bounds__(256) void gemm_k(
    const f16* __restrict__ A, int lda,
    const f16* __restrict__ Wt, long w_dstride,
    const float* __restrict__ bias, int b_dstride,
    f16* __restrict__ out16, float* __restrict__ out32,
    const int* __restrict__ offsets, const int* __restrict__ perm,
    int Ktot)
{
  __shared__ f16 As[BM * LDSP];
  __shared__ f16 Bs[BN * LDSP];

  int n0 = blockIdx.x * BN;
  int moff, count;
  if (MODE >= 1) {
    int d = blockIdx.z;
    int o0 = offsets[d], o1 = offsets[d + 1];
    if ((int)blockIdx.y * BM >= (o1 - o0)) return;
    moff = o0 + blockIdx.y * BM;
    count = o1;  // absolute end of this domain's slot range
    Wt += (long)d * w_dstride;
    bias += d * b_dstride;
  } else {
    moff = blockIdx.y * BM;
    count = B_TOT;
  }

  int t = threadIdx.x;
  int lane = t & 63;
  int wid = t >> 6;                       // 4 waves: 2x2 of 64x64
  int wm = (wid >> 1) * 64, wn = (wid & 1) * 64;
  int lr = lane & 15, lg = lane >> 4;

  f32x4 acc[4][4];
  #pragma unroll
  for (int m = 0; m < 4; m++)
    #pragma unroll
    for (int n = 0; n < 4; n++) acc[m][n] = f32x4{0.f, 0.f, 0.f, 0.f};

  // staging assignment: 512 16B-chunks per tile, 2 per thread
  int c0 = t, c1 = t + 256;
  int rA0 = c0 >> 2, ko0 = (c0 & 3) << 3;
  int rA1 = c1 >> 2, ko1 = (c1 & 3) << 3;
  bool v0 = (moff + rA0) < count, v1 = (moff + rA1) < count;
  long arow0, arow1;
  if (MODE == 1) {
    arow0 = v0 ? perm[moff + rA0] : 0;
    arow1 = v1 ? perm[moff + rA1] : 0;
  } else {
    arow0 = moff + rA0;
    arow1 = moff + rA1;
  }

  const uint4 z4 = make_uint4(0, 0, 0, 0);
  for (int kk = 0; kk < Ktot; kk += BK) {
    uint4 a0 = v0 ? *(const uint4*)(A + arow0 * lda + kk + ko0) : z4;
    uint4 a1 = v1 ? *(const uint4*)(A + arow1 * lda + kk + ko1) : z4;
    uint4 w0 = *(const uint4*)(Wt + (long)(n0 + rA0) * Ktot + kk + ko0);
    uint4 w1 = *(const uint4*)(Wt + (long)(n0 + rA1) * Ktot + kk + ko1);
    __syncthreads();  // previous iter's reads done before overwrite
    *(uint4*)&As[rA0 * LDSP + ko0] = a0;
    *(uint4*)&As[rA1 * LDSP + ko1] = a1;
    *(uint4*)&Bs[rA0 * LDSP + ko0] = w0;
    *(uint4*)&Bs[rA1 * LDSP + ko1] = w1;
    __syncthreads();

    f16x8 af[4], bf[4];
    #pragma unroll
    for (int m = 0; m < 4; m++)
      af[m] = *(const f16x8*)&As[(wm + m * 16 + lr) * LDSP + lg * 8];
    #pragma unroll
    for (int n = 0; n < 4; n++)
      bf[n] = *(const f16x8*)&Bs[(wn + n * 16 + lr) * LDSP + lg * 8];
    #pragma unroll
    for (int m = 0; m < 4; m++)
      #pragma unroll
      for (int n = 0; n < 4; n++)
        acc[m][n] = __builtin_amdgcn_mfma_f32_16x16x32_f16(af[m], bf[n], acc[m][n], 0, 0, 0);
  }

  // epilogue: C/D layout col = lane&15, row = (lane>>4)*4 + j
  float bcol[4];
  #pragma unroll
  for (int n = 0; n < 4; n++) {
    int cn = n0 + wn + n * 16 + lr;
    bcol[n] = (MODE == 3) ? ((cn < STY_) ? bias[cn] : 0.f) : bias[cn];
  }
  #pragma unroll
  for (int m = 0; m < 4; m++) {
    int rloc = wm + m * 16 + lg * 4;
    #pragma unroll
    for (int j = 0; j < 4; j++) {
      int r = moff + rloc + j;
      if (MODE >= 1 && r >= count) continue;
      #pragma unroll
      for (int n = 0; n < 4; n++) {
        int cn = n0 + wn + n * 16 + lr;
        float v = acc[m][n][j] + bcol[n];
        if (MODE == 3) {
          if (cn < STY_) out32[(long)perm[r] * STY_ + cn] = v;
        } else {
          out16[(long)r * HID_ + cn] = (f16)fmaxf(v, 0.f);
        }
      }
    }
  }
}

// ---------------- launch ----------------

extern "C" void kernel_launch(void* const* d_in, const int* in_sizes, int n_in,
                              void* d_out, int out_size, void* d_ws, size_t ws_size,
                              hipStream_t stream) {
  const float* x  = (const float*)d_in[0];
  const int*   y  = (const int*)  d_in[1];
  const float* W0 = (const float*)d_in[2];
  const float* b0 = (const float*)d_in[3];
  const float* W1 = (const float*)d_in[4];
  const float* b1 = (const float*)d_in[5];
  const float* W2 = (const float*)d_in[6];
  const float* b2 = (const float*)d_in[7];
  const float* W3 = (const float*)d_in[8];
  const float* b3 = (const float*)d_in[9];
  const float* U0 = (const float*)d_in[10];
  const float* c0 = (const float*)d_in[11];
  const float* U1 = (const float*)d_in[12];
  const float* c1 = (const float*)d_in[13];
  const float* U2 = (const float*)d_in[14];
  const float* c2 = (const float*)d_in[15];
  const float* U3 = (const float*)d_in[16];
  const float* c3 = (const float*)d_in[17];
  float* out = (float*)d_out;

  char* p = (char*)d_ws;
  auto alloc = [&](size_t bytes) -> char* {
    char* r = p; p += (bytes + 255) & ~(size_t)255; return r;
  };
  f16* x16 = (f16*)alloc((size_t)B_TOT * 32 * 2);
  f16* Wt0 = (f16*)alloc((size_t)512 * 32 * 2);
  f16* Wt1 = (f16*)alloc((size_t)512 * 512 * 2);
  f16* Wt2 = (f16*)alloc((size_t)512 * 512 * 2);
  f16* Wt3 = (f16*)alloc((size_t)512 * 512 * 2);
  f16* U0t = (f16*)alloc((size_t)ND_ * 512 * 512 * 2);
  f16* U1t = (f16*)alloc((size_t)ND_ * 512 * 512 * 2);
  f16* U2t = (f16*)alloc((size_t)ND_ * 512 * 512 * 2);
  f16* U3t = (f16*)alloc((size_t)ND_ * 128 * 512 * 2);  // N padded 64 -> 128
  f16* hA  = (f16*)alloc((size_t)B_TOT * HID_ * 2);
  f16* hB  = (f16*)alloc((size_t)B_TOT * HID_ * 2);
  int* counts  = (int*)alloc(ND_ * 4);
  int* offsets = (int*)alloc((ND_ + 1) * 4);
  int* cursors = (int*)alloc(ND_ * 4);
  int* perm    = (int*)alloc((size_t)B_TOT * 4);

  dim3 tb(32, 8);
  init_counts_k<<<1, 64, 0, stream>>>(counts, cursors);
  cast_x_k<<<(B_TOT * 32) / 256, 256, 0, stream>>>(x, x16);
  transpose_cast_k<<<dim3(16, 1, 1),  tb, 0, stream>>>(W0, Wt0, 16, 512, 32, 512, 0L, 0L);
  transpose_cast_k<<<dim3(16, 16, 1), tb, 0, stream>>>(W1, Wt1, 512, 512, 512, 512, 0L, 0L);
  transpose_cast_k<<<dim3(16, 16, 1), tb, 0, stream>>>(W2, Wt2, 512, 512, 512, 512, 0L, 0L);
  transpose_cast_k<<<dim3(16, 16, 1), tb, 0, stream>>>(W3, Wt3, 512, 512, 512, 512, 0L, 0L);
  transpose_cast_k<<<dim3(16, 16, ND_), tb, 0, stream>>>(U0, U0t, 512, 512, 512, 512, (long)512 * 512, (long)512 * 512);
  transpose_cast_k<<<dim3(16, 16, ND_), tb, 0, stream>>>(U1, U1t, 512, 512, 512, 512, (long)512 * 512, (long)512 * 512);
  transpose_cast_k<<<dim3(16, 16, ND_), tb, 0, stream>>>(U2, U2t, 512, 512, 512, 512, (long)512 * 512, (long)512 * 512);
  transpose_cast_k<<<dim3(4, 16, ND_),  tb, 0, stream>>>(U3, U3t, 512, 64, 512, 128, (long)512 * 64, (long)128 * 512);
  count_k<<<B_TOT / 256, 256, 0, stream>>>(y, counts);
  scan_k<<<1, 64, 0, stream>>>(counts, offsets, cursors);
  scatter_k<<<B_TOT / 256, 256, 0, stream>>>(y, cursors, perm);

  // trunk: x16 -> hA -> hB -> hA -> hB
  gemm_k<0><<<dim3(4, 128, 1), 256, 0, stream>>>(x16, 32, Wt0, 0L, b0, 0, hA, nullptr, nullptr, nullptr, 32);
  gemm_k<0><<<dim3(4, 128, 1), 256, 0, stream>>>(hA, 512, Wt1, 0L, b1, 0, hB, nullptr, nullptr, nullptr, 512);
  gemm_k<0><<<dim3(4, 128, 1), 256, 0, stream>>>(hB, 512, Wt2, 0L, b2, 0, hA, nullptr, nullptr, nullptr, 512);
  gemm_k<0><<<dim3(4, 128, 1), 256, 0, stream>>>(hA, 512, Wt3, 0L, b3, 0, hB, nullptr, nullptr, nullptr, 512);
  // experts (grouped by domain): hB -(gather)-> hA -> hB -> hA -(scatter)-> out
  gemm_k<1><<<dim3(4, 128, ND_), 256, 0, stream>>>(hB, 512, U0t, (long)512 * 512, c0, 512, hA, nullptr, offsets, perm, 512);
  gemm_k<2><<<dim3(4, 128, ND_), 256, 0, stream>>>(hA, 512, U1t, (long)512 * 512, c1, 512, hB, nullptr, offsets, perm, 512);
  gemm_k<2><<<dim3(4, 128, ND_), 256, 0, stream>>>(hB, 512, U2t, (long)512 * 512, c2, 512, hA, nullptr, offsets, perm, 512);
  gemm_k<3><<<dim3(1, 128, ND_), 256, 0, stream>>>(hA, 512, U3t, (long)128 * 512, c3, 64, nullptr, out, offsets, perm, 512);
}

// Round 2
// 218.350 us; speedup vs baseline: 1.5547x; 1.5547x over previous
//
#include <hip/hip_runtime.h>

typedef _Float16 f16;
typedef _Float16 f16x8 __attribute__((ext_vector_type(8)));
typedef float f32x4 __attribute__((ext_vector_type(4)));

#define B_TOT 16384
#define HID_  512
#define LAT_  16
#define STY_  64
#define ND_   8

#define BM 128
#define BN 128
#define BK 32
#define LDSP 40   // padded LDS row stride in f16 (80 B rows; 16B-aligned, 2-way banks = free)

// ---------------- prep kernels ----------------

__global__ void cast_x_k(const float* __restrict__ x, f16* __restrict__ x16) {
  int i = blockIdx.x * blockDim.x + threadIdx.x;  // over B_TOT*32
  int b = i >> 5, k = i & 31;
  x16[i] = (k < LAT_) ? (f16)x[b * LAT_ + k] : (f16)0.f;
}

// in: f32 [Kin][Nin] (+batch), out: f16 [Npad][Kpad] (+batch), zero padded.
__global__ void transpose_cast_k(const float* __restrict__ in, f16* __restrict__ out,
                                 int Kin, int Nin, int Kpad, int Npad,
                                 long isb, long osb) {
  __shared__ float tile[32][33];
  const float* ip = in + (long)blockIdx.z * isb;
  f16* op = out + (long)blockIdx.z * osb;
  int k0 = blockIdx.y * 32, n0 = blockIdx.x * 32;
  int tx = threadIdx.x, ty = threadIdx.y;  // 32 x 8
  #pragma unroll
  for (int i = 0; i < 32; i += 8) {
    int k = k0 + ty + i, n = n0 + tx;
    tile[ty + i][tx] = (k < Kin && n < Nin) ? ip[(long)k * Nin + n] : 0.f;
  }
  __syncthreads();
  #pragma unroll
  for (int i = 0; i < 32; i += 8) {
    int n = n0 + ty + i, k = k0 + tx;
    if (n < Npad && k < Kpad) op[(long)n * Kpad + k] = (f16)tile[tx][ty + i];
  }
}

// Deterministic atomics-free bucketing: one block, 1024 threads, 16 rows each.
// Produces offsets[0..8] (domain slot ranges) and perm (slot -> source row),
// sorted by (domain, row index).
#define NT_BUCKET 1024
#define RPT 16

__global__ __launch_bounds__(NT_BUCKET) void bucket_k(const int* __restrict__ y,
                                                      int* __restrict__ offsets,
                                                      int* __restrict__ perm) {
  __shared__ int hist[ND_][NT_BUCKET];   // 32 KB; thread t owns column t
  __shared__ int totals[ND_];
  __shared__ int bases[ND_ + 1];
  int t = threadIdx.x;
  int base = t * RPT;

  #pragma unroll
  for (int d = 0; d < ND_; d++) hist[d][t] = 0;
  // no barrier needed: each thread touches only its own column
  int yv[RPT];
  #pragma unroll
  for (int i = 0; i < RPT; i++) {
    yv[i] = y[base + i];
    hist[yv[i]][t]++;
  }
  __syncthreads();

  // per-domain exclusive scan over the 1024 thread-columns; wave w = domain w
  int wave = t >> 6, lane = t & 63;
  if (wave < ND_) {
    int d = wave;
    int carry = 0;
    for (int c = 0; c < NT_BUCKET; c += 64) {
      int v = hist[d][c + lane];
      int s = v;
      #pragma unroll
      for (int off = 1; off < 64; off <<= 1) {
        int u = __shfl_up(s, off, 64);
        if (lane >= off) s += u;
      }
      hist[d][c + lane] = carry + s - v;   // exclusive prefix
      carry += __shfl(s, 63, 64);
    }
    if (lane == 0) totals[d] = carry;
  }
  __syncthreads();

  if (t == 0) {
    int s = 0;
    #pragma unroll
    for (int d = 0; d < ND_; d++) { bases[d] = s; offsets[d] = s; s += totals[d]; }
    bases[ND_] = s; offsets[ND_] = s;
  }
  __syncthreads();

  #pragma unroll
  for (int i = 0; i < RPT; i++) {
    int d = yv[i];
    int pos = bases[d] + hist[d][t];
    hist[d][t]++;
    perm[pos] = base + i;
  }
}

// ---------------- GEMM ----------------
// C[M,N] = act(A[M,K] @ W[K,N] + bias) ; W passed pre-transposed f16 [N][Ktot].
// MODE 0: trunk         — rows = blockIdx.y*BM.., fp16 relu out
// MODE 1: expert first  — per-domain tiles, A rows gathered via perm, fp16 relu out at slots
// MODE 2: expert mid    — per-domain tiles, contiguous slots in/out, fp16 relu out
// MODE 3: expert last   — per-domain tiles, scatter f32 out via perm, no relu, N=64 mask
template<int MODE>
__global__ __launch_bounds__(256) void gemm_k(
    const f16* __restrict__ A, int lda,
    const f16* __restrict__ Wt, long w_dstride,
    const float* __restrict__ bias, int b_dstride,
    f16* __restrict__ out16, float* __restrict__ out32,
    const int* __restrict__ offsets, const int* __restrict__ perm,
    int Ktot)
{
  __shared__ f16 As[BM * LDSP];
  __shared__ f16 Bs[BN * LDSP];

  int n0 = blockIdx.x * BN;
  int moff, count;
  if (MODE >= 1) {
    int d = blockIdx.z;
    int o0 = offsets[d], o1 = offsets[d + 1];
    if ((int)blockIdx.y * BM >= (o1 - o0)) return;
    moff = o0 + blockIdx.y * BM;
    count = o1;  // absolute end of this domain's slot range
    Wt += (long)d * w_dstride;
    bias += d * b_dstride;
  } else {
    moff = blockIdx.y * BM;
    count = B_TOT;
  }

  int t = threadIdx.x;
  int lane = t & 63;
  int wid = t >> 6;                       // 4 waves: 2x2 of 64x64
  int wm = (wid >> 1) * 64, wn = (wid & 1) * 64;
  int lr = lane & 15, lg = lane >> 4;

  f32x4 acc[4][4];
  #pragma unroll
  for (int m = 0; m < 4; m++)
    #pragma unroll
    for (int n = 0; n < 4; n++) acc[m][n] = f32x4{0.f, 0.f, 0.f, 0.f};

  // staging assignment: 512 16B-chunks per tile, 2 per thread
  int c0 = t, c1 = t + 256;
  int rA0 = c0 >> 2, ko0 = (c0 & 3) << 3;
  int rA1 = c1 >> 2, ko1 = (c1 & 3) << 3;
  bool v0 = (moff + rA0) < count, v1 = (moff + rA1) < count;
  long arow0, arow1;
  if (MODE == 1) {
    arow0 = v0 ? perm[moff + rA0] : 0;
    arow1 = v1 ? perm[moff + rA1] : 0;
  } else {
    arow0 = moff + rA0;
    arow1 = moff + rA1;
  }

  const uint4 z4 = make_uint4(0, 0, 0, 0);
  for (int kk = 0; kk < Ktot; kk += BK) {
    uint4 a0 = v0 ? *(const uint4*)(A + arow0 * lda + kk + ko0) : z4;
    uint4 a1 = v1 ? *(const uint4*)(A + arow1 * lda + kk + ko1) : z4;
    uint4 w0 = *(const uint4*)(Wt + (long)(n0 + rA0) * Ktot + kk + ko0);
    uint4 w1 = *(const uint4*)(Wt + (long)(n0 + rA1) * Ktot + kk + ko1);
    __syncthreads();  // previous iter's reads done before overwrite
    *(uint4*)&As[rA0 * LDSP + ko0] = a0;
    *(uint4*)&As[rA1 * LDSP + ko1] = a1;
    *(uint4*)&Bs[rA0 * LDSP + ko0] = w0;
    *(uint4*)&Bs[rA1 * LDSP + ko1] = w1;
    __syncthreads();

    f16x8 af[4], bf[4];
    #pragma unroll
    for (int m = 0; m < 4; m++)
      af[m] = *(const f16x8*)&As[(wm + m * 16 + lr) * LDSP + lg * 8];
    #pragma unroll
    for (int n = 0; n < 4; n++)
      bf[n] = *(const f16x8*)&Bs[(wn + n * 16 + lr) * LDSP + lg * 8];
    #pragma unroll
    for (int m = 0; m < 4; m++)
      #pragma unroll
      for (int n = 0; n < 4; n++)
        acc[m][n] = __builtin_amdgcn_mfma_f32_16x16x32_f16(af[m], bf[n], acc[m][n], 0, 0, 0);
  }

  // epilogue: C/D layout col = lane&15, row = (lane>>4)*4 + j
  float bcol[4];
  #pragma unroll
  for (int n = 0; n < 4; n++) {
    int cn = n0 + wn + n * 16 + lr;
    bcol[n] = (MODE == 3) ? ((cn < STY_) ? bias[cn] : 0.f) : bias[cn];
  }
  #pragma unroll
  for (int m = 0; m < 4; m++) {
    int rloc = wm + m * 16 + lg * 4;
    #pragma unroll
    for (int j = 0; j < 4; j++) {
      int r = moff + rloc + j;
      if (MODE >= 1 && r >= count) continue;
      #pragma unroll
      for (int n = 0; n < 4; n++) {
        int cn = n0 + wn + n * 16 + lr;
        float v = acc[m][n][j] + bcol[n];
        if (MODE == 3) {
          if (cn < STY_) out32[(long)perm[r] * STY_ + cn] = v;
        } else {
          out16[(long)r * HID_ + cn] = (f16)fmaxf(v, 0.f);
        }
      }
    }
  }
}

// ---------------- launch ----------------

extern "C" void kernel_launch(void* const* d_in, const int* in_sizes, int n_in,
                              void* d_out, int out_size, void* d_ws, size_t ws_size,
                              hipStream_t stream) {
  const float* x  = (const float*)d_in[0];
  const int*   y  = (const int*)  d_in[1];
  const float* W0 = (const float*)d_in[2];
  const float* b0 = (const float*)d_in[3];
  const float* W1 = (const float*)d_in[4];
  const float* b1 = (const float*)d_in[5];
  const float* W2 = (const float*)d_in[6];
  const float* b2 = (const float*)d_in[7];
  const float* W3 = (const float*)d_in[8];
  const float* b3 = (const float*)d_in[9];
  const float* U0 = (const float*)d_in[10];
  const float* c0 = (const float*)d_in[11];
  const float* U1 = (const float*)d_in[12];
  const float* c1 = (const float*)d_in[13];
  const float* U2 = (const float*)d_in[14];
  const float* c2 = (const float*)d_in[15];
  const float* U3 = (const float*)d_in[16];
  const float* c3 = (const float*)d_in[17];
  float* out = (float*)d_out;

  char* p = (char*)d_ws;
  auto alloc = [&](size_t bytes) -> char* {
    char* r = p; p += (bytes + 255) & ~(size_t)255; return r;
  };
  f16* x16 = (f16*)alloc((size_t)B_TOT * 32 * 2);
  f16* Wt0 = (f16*)alloc((size_t)512 * 32 * 2);
  f16* Wt1 = (f16*)alloc((size_t)512 * 512 * 2);
  f16* Wt2 = (f16*)alloc((size_t)512 * 512 * 2);
  f16* Wt3 = (f16*)alloc((size_t)512 * 512 * 2);
  f16* U0t = (f16*)alloc((size_t)ND_ * 512 * 512 * 2);
  f16* U1t = (f16*)alloc((size_t)ND_ * 512 * 512 * 2);
  f16* U2t = (f16*)alloc((size_t)ND_ * 512 * 512 * 2);
  f16* U3t = (f16*)alloc((size_t)ND_ * 128 * 512 * 2);  // N padded 64 -> 128
  f16* hA  = (f16*)alloc((size_t)B_TOT * HID_ * 2);
  f16* hB  = (f16*)alloc((size_t)B_TOT * HID_ * 2);
  int* offsets = (int*)alloc((ND_ + 1) * 4);
  int* perm    = (int*)alloc((size_t)B_TOT * 4);

  dim3 tb(32, 8);
  cast_x_k<<<(B_TOT * 32) / 256, 256, 0, stream>>>(x, x16);
  transpose_cast_k<<<dim3(16, 1, 1),  tb, 0, stream>>>(W0, Wt0, 16, 512, 32, 512, 0L, 0L);
  transpose_cast_k<<<dim3(16, 16, 1), tb, 0, stream>>>(W1, Wt1, 512, 512, 512, 512, 0L, 0L);
  transpose_cast_k<<<dim3(16, 16, 1), tb, 0, stream>>>(W2, Wt2, 512, 512, 512, 512, 0L, 0L);
  transpose_cast_k<<<dim3(16, 16, 1), tb, 0, stream>>>(W3, Wt3, 512, 512, 512, 512, 0L, 0L);
  transpose_cast_k<<<dim3(16, 16, ND_), tb, 0, stream>>>(U0, U0t, 512, 512, 512, 512, (long)512 * 512, (long)512 * 512);
  transpose_cast_k<<<dim3(16, 16, ND_), tb, 0, stream>>>(U1, U1t, 512, 512, 512, 512, (long)512 * 512, (long)512 * 512);
  transpose_cast_k<<<dim3(16, 16, ND_), tb, 0, stream>>>(U2, U2t, 512, 512, 512, 512, (long)512 * 512, (long)512 * 512);
  transpose_cast_k<<<dim3(4, 16, ND_),  tb, 0, stream>>>(U3, U3t, 512, 64, 512, 128, (long)512 * 64, (long)128 * 512);
  bucket_k<<<1, NT_BUCKET, 0, stream>>>(y, offsets, perm);

  // trunk: x16 -> hA -> hB -> hA -> hB
  gemm_k<0><<<dim3(4, 128, 1), 256, 0, stream>>>(x16, 32, Wt0, 0L, b0, 0, hA, nullptr, nullptr, nullptr, 32);
  gemm_k<0><<<dim3(4, 128, 1), 256, 0, stream>>>(hA, 512, Wt1, 0L, b1, 0, hB, nullptr, nullptr, nullptr, 512);
  gemm_k<0><<<dim3(4, 128, 1), 256, 0, stream>>>(hB, 512, Wt2, 0L, b2, 0, hA, nullptr, nullptr, nullptr, 512);
  gemm_k<0><<<dim3(4, 128, 1), 256, 0, stream>>>(hA, 512, Wt3, 0L, b3, 0, hB, nullptr, nullptr, nullptr, 512);
  // experts (grouped by domain): hB -(gather)-> hA -> hB -> hA -(scatter)-> out
  gemm_k<1><<<dim3(4, 128, ND_), 256, 0, stream>>>(hB, 512, U0t, (long)512 * 512, c0, 512, hA, nullptr, offsets, perm, 512);
  gemm_k<2><<<dim3(4, 128, ND_), 256, 0, stream>>>(hA, 512, U1t, (long)512 * 512, c1, 512, hB, nullptr, offsets, perm, 512);
  gemm_k<2><<<dim3(4, 128, ND_), 256, 0, stream>>>(hB, 512, U2t, (long)512 * 512, c2, 512, hA, nullptr, offsets, perm, 512);
  gemm_k<3><<<dim3(1, 128, ND_), 256, 0, stream>>>(hA, 512, U3t, (long)128 * 512, c3, 64, nullptr, out, offsets, perm, 512);
}

// Round 3
// 196.513 us; speedup vs baseline: 1.7275x; 1.1111x over previous
//
#include <hip/hip_runtime.h>

typedef _Float16 f16;
typedef _Float16 f16x8 __attribute__((ext_vector_type(8)));
typedef float f32x4 __attribute__((ext_vector_type(4)));

#define B_TOT 16384
#define HID_  512
#define LAT_  16
#define STY_  64
#define ND_   8

#define BM 128
#define BN 128
#define BK 32

// async global->LDS, 16B per lane; LDS dest must be wave-uniform base (+lane*16)
__device__ __forceinline__ void gload16(const f16* g, f16* l) {
  __builtin_amdgcn_global_load_lds(
      (const __attribute__((address_space(1))) unsigned int*)g,
      (__attribute__((address_space(3))) unsigned int*)l,
      16, 0, 0);
}

// ---------------- prep kernels ----------------

__global__ void cast_x_k(const float* __restrict__ x, f16* __restrict__ x16) {
  int i = blockIdx.x * blockDim.x + threadIdx.x;  // over B_TOT*32
  int b = i >> 5, k = i & 31;
  x16[i] = (k < LAT_) ? (f16)x[b * LAT_ + k] : (f16)0.f;
}

// One launch transposes+casts ALL weight tensors. blockIdx.z selects a slice:
// z=0: W0 (16x512 -> [512][32]);  z=1..3: W1..W3 (512x512 -> [512][512])
// z=4..11: U0 slices; 12..19: U1; 20..27: U2  (512x512 -> [512][512])
// z=28..35: U3 slices (512x64 -> [128][512], rows 64..127 zero)
__global__ void prep_k(const float* W0, f16* Wt0, const float* W1, f16* Wt1,
                       const float* W2, f16* Wt2, const float* W3, f16* Wt3,
                       const float* U0, f16* U0t, const float* U1, f16* U1t,
                       const float* U2, f16* U2t, const float* U3, f16* U3t) {
  int z = blockIdx.z;
  const float* src; f16* dst; int Kin, Nin, Kpad, Npad;
  if (z == 0)      { src = W0; dst = Wt0; Kin = 16;  Nin = 512; Kpad = 32;  Npad = 512; }
  else if (z == 1) { src = W1; dst = Wt1; Kin = 512; Nin = 512; Kpad = 512; Npad = 512; }
  else if (z == 2) { src = W2; dst = Wt2; Kin = 512; Nin = 512; Kpad = 512; Npad = 512; }
  else if (z == 3) { src = W3; dst = Wt3; Kin = 512; Nin = 512; Kpad = 512; Npad = 512; }
  else if (z < 12) { int d = z - 4;  src = U0 + (long)d * 262144; dst = U0t + (long)d * 262144; Kin = 512; Nin = 512; Kpad = 512; Npad = 512; }
  else if (z < 20) { int d = z - 12; src = U1 + (long)d * 262144; dst = U1t + (long)d * 262144; Kin = 512; Nin = 512; Kpad = 512; Npad = 512; }
  else if (z < 28) { int d = z - 20; src = U2 + (long)d * 262144; dst = U2t + (long)d * 262144; Kin = 512; Nin = 512; Kpad = 512; Npad = 512; }
  else             { int d = z - 28; src = U3 + (long)d * 32768;  dst = U3t + (long)d * 65536;  Kin = 512; Nin = 64;  Kpad = 512; Npad = 128; }

  __shared__ float tile[32][33];
  int k0 = blockIdx.y * 32, n0 = blockIdx.x * 32;
  int tx = threadIdx.x, ty = threadIdx.y;  // 32 x 8
  #pragma unroll
  for (int i = 0; i < 32; i += 8) {
    int k = k0 + ty + i, n = n0 + tx;
    tile[ty + i][tx] = (k < Kin && n < Nin) ? src[(long)k * Nin + n] : 0.f;
  }
  __syncthreads();
  #pragma unroll
  for (int i = 0; i < 32; i += 8) {
    int n = n0 + ty + i, k = k0 + tx;
    if (n < Npad && k < Kpad) dst[(long)n * Kpad + k] = (f16)tile[tx][ty + i];
  }
}

// Deterministic atomics-free bucketing: one block, 1024 threads, 16 rows each.
#define NT_BUCKET 1024
#define RPT 16

__global__ __launch_bounds__(NT_BUCKET) void bucket_k(const int* __restrict__ y,
                                                      int* __restrict__ offsets,
                                                      int* __restrict__ perm) {
  __shared__ int hist[ND_][NT_BUCKET];   // 32 KB; thread t owns column t
  __shared__ int totals[ND_];
  __shared__ int bases[ND_ + 1];
  int t = threadIdx.x;
  int base = t * RPT;

  #pragma unroll
  for (int d = 0; d < ND_; d++) hist[d][t] = 0;
  int yv[RPT];
  #pragma unroll
  for (int i = 0; i < RPT; i++) {
    yv[i] = y[base + i];
    hist[yv[i]][t]++;
  }
  __syncthreads();

  int wave = t >> 6, lane = t & 63;
  if (wave < ND_) {
    int d = wave;
    int carry = 0;
    for (int c = 0; c < NT_BUCKET; c += 64) {
      int v = hist[d][c + lane];
      int s = v;
      #pragma unroll
      for (int off = 1; off < 64; off <<= 1) {
        int u = __shfl_up(s, off, 64);
        if (lane >= off) s += u;
      }
      hist[d][c + lane] = carry + s - v;   // exclusive prefix
      carry += __shfl(s, 63, 64);
    }
    if (lane == 0) totals[d] = carry;
  }
  __syncthreads();

  if (t == 0) {
    int s = 0;
    #pragma unroll
    for (int d = 0; d < ND_; d++) { bases[d] = s; offsets[d] = s; s += totals[d]; }
    bases[ND_] = s; offsets[ND_] = s;
  }
  __syncthreads();

  #pragma unroll
  for (int i = 0; i < RPT; i++) {
    int d = yv[i];
    int pos = bases[d] + hist[d][t];
    hist[d][t]++;
    perm[pos] = base + i;
  }
}

// ---------------- GEMM ----------------
// C[M,N] = act(A[M,K] @ W[K,N] + bias) ; W pre-transposed f16 [N][Ktot].
// MODE 0: trunk; 1: expert first (gather A via perm); 2: expert mid; 3: expert last
// (scatter f32 out via perm, no relu, N=64 mask).
// Staging: global_load_lds 16B/lane into linear LDS [128][32] f16 per tile.
template<int MODE>
__global__ __launch_bounds__(256) void gemm_k(
    const f16* __restrict__ A, int lda,
    const f16* __restrict__ Wt, long w_dstride,
    const float* __restrict__ bias, int b_dstride,
    f16* __restrict__ out16, float* __restrict__ out32,
    const int* __restrict__ offsets, const int* __restrict__ perm,
    int Ktot)
{
  __shared__ f16 As[BM * BK];   // 8 KB, linear (global_load_lds needs linear dest)
  __shared__ f16 Bs[BN * BK];   // 8 KB

  int n0 = blockIdx.x * BN;
  int moff, count;
  if (MODE >= 1) {
    int d = blockIdx.z;
    int o0 = offsets[d], o1 = offsets[d + 1];
    if ((int)blockIdx.y * BM >= (o1 - o0)) return;
    moff = o0 + blockIdx.y * BM;
    count = o1;  // absolute end of this domain's slot range
    Wt += (long)d * w_dstride;
    bias += d * b_dstride;
  } else {
    moff = blockIdx.y * BM;
    count = B_TOT;
  }

  int t = threadIdx.x;
  int lane = t & 63;
  int wid = t >> 6;                       // 4 waves: 2x2 of 64x64
  int wm = (wid >> 1) * 64, wn = (wid & 1) * 64;
  int lr = lane & 15, lg = lane >> 4;

  // staging geometry: chunk = 16B; thread t covers (row = t>>2, col = (t&3)*8)
  // issue0 -> rows 0..63, issue1 -> rows 64..127. LDS dest per wave:
  // base + issue*2048 + wid*512 (f16 elems) == row-major linear match.
  int rs = t >> 2;
  int cs = (t & 3) << 3;
  long arow0, arow1;
  {
    int s0 = moff + rs, s1 = moff + 64 + rs;
    if (MODE >= 1) {
      s0 = (s0 < count) ? s0 : count - 1;   // clamp: garbage rows discarded in epilogue
      s1 = (s1 < count) ? s1 : count - 1;
    }
    if (MODE == 1) { arow0 = perm[s0]; arow1 = perm[s1]; }
    else           { arow0 = s0;       arow1 = s1; }
  }
  const f16* wp0 = Wt + (long)(n0 + rs) * Ktot + cs;
  const f16* wp1 = Wt + (long)(n0 + 64 + rs) * Ktot + cs;
  const f16* ap0 = A + arow0 * lda + cs;
  const f16* ap1 = A + arow1 * lda + cs;
  f16* asl = &As[wid * 512];
  f16* ash = &As[2048 + wid * 512];
  f16* bsl = &Bs[wid * 512];
  f16* bsh = &Bs[2048 + wid * 512];

  f32x4 acc[4][4];
  #pragma unroll
  for (int m = 0; m < 4; m++)
    #pragma unroll
    for (int n = 0; n < 4; n++) acc[m][n] = f32x4{0.f, 0.f, 0.f, 0.f};

  for (int kk = 0; kk < Ktot; kk += BK) {
    __syncthreads();                       // prev iter's LDS reads done
    gload16(ap0 + kk, asl);
    gload16(ap1 + kk, ash);
    gload16(wp0 + kk, bsl);
    gload16(wp1 + kk, bsh);
    __syncthreads();                       // compiler drains vmcnt before barrier

    f16x8 af[4], bf[4];
    #pragma unroll
    for (int m = 0; m < 4; m++)
      af[m] = *(const f16x8*)&As[(wm + m * 16 + lr) * BK + lg * 8];
    #pragma unroll
    for (int n = 0; n < 4; n++)
      bf[n] = *(const f16x8*)&Bs[(wn + n * 16 + lr) * BK + lg * 8];
    #pragma unroll
    for (int m = 0; m < 4; m++)
      #pragma unroll
      for (int n = 0; n < 4; n++)
        acc[m][n] = __builtin_amdgcn_mfma_f32_16x16x32_f16(af[m], bf[n], acc[m][n], 0, 0, 0);
  }

  // epilogue: C/D layout col = lane&15, row = (lane>>4)*4 + j
  float bcol[4];
  #pragma unroll
  for (int n = 0; n < 4; n++) {
    int cn = n0 + wn + n * 16 + lr;
    bcol[n] = (MODE == 3) ? ((cn < STY_) ? bias[cn] : 0.f) : bias[cn];
  }
  #pragma unroll
  for (int m = 0; m < 4; m++) {
    int rloc = wm + m * 16 + lg * 4;
    #pragma unroll
    for (int j = 0; j < 4; j++) {
      int r = moff + rloc + j;
      if (MODE >= 1 && r >= count) continue;
      #pragma unroll
      for (int n = 0; n < 4; n++) {
        int cn = n0 + wn + n * 16 + lr;
        float v = acc[m][n][j] + bcol[n];
        if (MODE == 3) {
          if (cn < STY_) out32[(long)perm[r] * STY_ + cn] = v;
        } else {
          out16[(long)r * HID_ + cn] = (f16)fmaxf(v, 0.f);
        }
      }
    }
  }
}

// ---------------- launch ----------------

extern "C" void kernel_launch(void* const* d_in, const int* in_sizes, int n_in,
                              void* d_out, int out_size, void* d_ws, size_t ws_size,
                              hipStream_t stream) {
  const float* x  = (const float*)d_in[0];
  const int*   y  = (const int*)  d_in[1];
  const float* W0 = (const float*)d_in[2];
  const float* b0 = (const float*)d_in[3];
  const float* W1 = (const float*)d_in[4];
  const float* b1 = (const float*)d_in[5];
  const float* W2 = (const float*)d_in[6];
  const float* b2 = (const float*)d_in[7];
  const float* W3 = (const float*)d_in[8];
  const float* b3 = (const float*)d_in[9];
  const float* U0 = (const float*)d_in[10];
  const float* c0 = (const float*)d_in[11];
  const float* U1 = (const float*)d_in[12];
  const float* c1 = (const float*)d_in[13];
  const float* U2 = (const float*)d_in[14];
  const float* c2 = (const float*)d_in[15];
  const float* U3 = (const float*)d_in[16];
  const float* c3 = (const float*)d_in[17];
  float* out = (float*)d_out;

  char* p = (char*)d_ws;
  auto alloc = [&](size_t bytes) -> char* {
    char* r = p; p += (bytes + 255) & ~(size_t)255; return r;
  };
  f16* x16 = (f16*)alloc((size_t)B_TOT * 32 * 2);
  f16* Wt0 = (f16*)alloc((size_t)512 * 32 * 2);
  f16* Wt1 = (f16*)alloc((size_t)512 * 512 * 2);
  f16* Wt2 = (f16*)alloc((size_t)512 * 512 * 2);
  f16* Wt3 = (f16*)alloc((size_t)512 * 512 * 2);
  f16* U0t = (f16*)alloc((size_t)ND_ * 512 * 512 * 2);
  f16* U1t = (f16*)alloc((size_t)ND_ * 512 * 512 * 2);
  f16* U2t = (f16*)alloc((size_t)ND_ * 512 * 512 * 2);
  f16* U3t = (f16*)alloc((size_t)ND_ * 128 * 512 * 2);  // N padded 64 -> 128
  f16* hA  = (f16*)alloc((size_t)B_TOT * HID_ * 2);
  f16* hB  = (f16*)alloc((size_t)B_TOT * HID_ * 2);
  int* offsets = (int*)alloc((ND_ + 1) * 4);
  int* perm    = (int*)alloc((size_t)B_TOT * 4);

  cast_x_k<<<(B_TOT * 32) / 256, 256, 0, stream>>>(x, x16);
  prep_k<<<dim3(16, 16, 36), dim3(32, 8), 0, stream>>>(W0, Wt0, W1, Wt1, W2, Wt2, W3, Wt3,
                                                       U0, U0t, U1, U1t, U2, U2t, U3, U3t);
  bucket_k<<<1, NT_BUCKET, 0, stream>>>(y, offsets, perm);

  // trunk: x16 -> hA -> hB -> hA -> hB
  gemm_k<0><<<dim3(4, 128, 1), 256, 0, stream>>>(x16, 32, Wt0, 0L, b0, 0, hA, nullptr, nullptr, nullptr, 32);
  gemm_k<0><<<dim3(4, 128, 1), 256, 0, stream>>>(hA, 512, Wt1, 0L, b1, 0, hB, nullptr, nullptr, nullptr, 512);
  gemm_k<0><<<dim3(4, 128, 1), 256, 0, stream>>>(hB, 512, Wt2, 0L, b2, 0, hA, nullptr, nullptr, nullptr, 512);
  gemm_k<0><<<dim3(4, 128, 1), 256, 0, stream>>>(hA, 512, Wt3, 0L, b3, 0, hB, nullptr, nullptr, nullptr, 512);
  // experts (grouped by domain): hB -(gather)-> hA -> hB -> hA -(scatter)-> out
  gemm_k<1><<<dim3(4, 128, ND_), 256, 0, stream>>>(hB, 512, U0t, (long)512 * 512, c0, 512, hA, nullptr, offsets, perm, 512);
  gemm_k<2><<<dim3(4, 128, ND_), 256, 0, stream>>>(hA, 512, U1t, (long)512 * 512, c1, 512, hB, nullptr, offsets, perm, 512);
  gemm_k<2><<<dim3(4, 128, ND_), 256, 0, stream>>>(hB, 512, U2t, (long)512 * 512, c2, 512, hA, nullptr, offsets, perm, 512);
  gemm_k<3><<<dim3(1, 128, ND_), 256, 0, stream>>>(hA, 512, U3t, (long)128 * 512, c3, 64, nullptr, out, offsets, perm, 512);
}

// Round 4
// 192.939 us; speedup vs baseline: 1.7595x; 1.0185x over previous
//
#include <hip/hip_runtime.h>

typedef _Float16 f16;
typedef _Float16 f16x8 __attribute__((ext_vector_type(8)));
typedef float f32x4 __attribute__((ext_vector_type(4)));

#define B_TOT 16384
#define HID_  512
#define LAT_  16
#define STY_  64
#define ND_   8

#define BM 128
#define BN 128
#define BK 32

// async global->LDS, 16B per lane; LDS dest must be wave-uniform base (+lane*16)
__device__ __forceinline__ void gload16(const f16* g, f16* l) {
  __builtin_amdgcn_global_load_lds(
      (const __attribute__((address_space(1))) unsigned int*)g,
      (__attribute__((address_space(3))) unsigned int*)l,
      16, 0, 0);
}

// ---------------- prep kernels ----------------

__global__ void cast_x_k(const float* __restrict__ x, f16* __restrict__ x16) {
  int i = blockIdx.x * blockDim.x + threadIdx.x;  // over B_TOT*32
  int b = i >> 5, k = i & 31;
  x16[i] = (k < LAT_) ? (f16)x[b * LAT_ + k] : (f16)0.f;
}

// One launch transposes+casts ALL weight tensors. blockIdx.z selects a slice:
// z=0: W0 (16x512 -> [512][32]);  z=1..3: W1..W3 (512x512 -> [512][512])
// z=4..11: U0 slices; 12..19: U1; 20..27: U2  (512x512 -> [512][512])
// z=28..35: U3 slices (512x64 -> [128][512], rows 64..127 zero)
__global__ void prep_k(const float* W0, f16* Wt0, const float* W1, f16* Wt1,
                       const float* W2, f16* Wt2, const float* W3, f16* Wt3,
                       const float* U0, f16* U0t, const float* U1, f16* U1t,
                       const float* U2, f16* U2t, const float* U3, f16* U3t) {
  int z = blockIdx.z;
  const float* src; f16* dst; int Kin, Nin, Kpad, Npad;
  if (z == 0)      { src = W0; dst = Wt0; Kin = 16;  Nin = 512; Kpad = 32;  Npad = 512; }
  else if (z == 1) { src = W1; dst = Wt1; Kin = 512; Nin = 512; Kpad = 512; Npad = 512; }
  else if (z == 2) { src = W2; dst = Wt2; Kin = 512; Nin = 512; Kpad = 512; Npad = 512; }
  else if (z == 3) { src = W3; dst = Wt3; Kin = 512; Nin = 512; Kpad = 512; Npad = 512; }
  else if (z < 12) { int d = z - 4;  src = U0 + (long)d * 262144; dst = U0t + (long)d * 262144; Kin = 512; Nin = 512; Kpad = 512; Npad = 512; }
  else if (z < 20) { int d = z - 12; src = U1 + (long)d * 262144; dst = U1t + (long)d * 262144; Kin = 512; Nin = 512; Kpad = 512; Npad = 512; }
  else if (z < 28) { int d = z - 20; src = U2 + (long)d * 262144; dst = U2t + (long)d * 262144; Kin = 512; Nin = 512; Kpad = 512; Npad = 512; }
  else             { int d = z - 28; src = U3 + (long)d * 32768;  dst = U3t + (long)d * 65536;  Kin = 512; Nin = 64;  Kpad = 512; Npad = 128; }

  __shared__ float tile[32][33];
  int k0 = blockIdx.y * 32, n0 = blockIdx.x * 32;
  int tx = threadIdx.x, ty = threadIdx.y;  // 32 x 8
  #pragma unroll
  for (int i = 0; i < 32; i += 8) {
    int k = k0 + ty + i, n = n0 + tx;
    tile[ty + i][tx] = (k < Kin && n < Nin) ? src[(long)k * Nin + n] : 0.f;
  }
  __syncthreads();
  #pragma unroll
  for (int i = 0; i < 32; i += 8) {
    int n = n0 + ty + i, k = k0 + tx;
    if (n < Npad && k < Kpad) dst[(long)n * Kpad + k] = (f16)tile[tx][ty + i];
  }
}

// Deterministic atomics-free bucketing: one block, 1024 threads, 16 rows each.
#define NT_BUCKET 1024
#define RPT 16

__global__ __launch_bounds__(NT_BUCKET) void bucket_k(const int* __restrict__ y,
                                                      int* __restrict__ offsets,
                                                      int* __restrict__ perm) {
  __shared__ int hist[ND_][NT_BUCKET];   // 32 KB; thread t owns column t
  __shared__ int totals[ND_];
  __shared__ int bases[ND_ + 1];
  int t = threadIdx.x;
  int base = t * RPT;

  #pragma unroll
  for (int d = 0; d < ND_; d++) hist[d][t] = 0;
  int yv[RPT];
  #pragma unroll
  for (int i = 0; i < RPT; i++) {
    yv[i] = y[base + i];
    hist[yv[i]][t]++;
  }
  __syncthreads();

  int wave = t >> 6, lane = t & 63;
  if (wave < ND_) {
    int d = wave;
    int carry = 0;
    for (int c = 0; c < NT_BUCKET; c += 64) {
      int v = hist[d][c + lane];
      int s = v;
      #pragma unroll
      for (int off = 1; off < 64; off <<= 1) {
        int u = __shfl_up(s, off, 64);
        if (lane >= off) s += u;
      }
      hist[d][c + lane] = carry + s - v;   // exclusive prefix
      carry += __shfl(s, 63, 64);
    }
    if (lane == 0) totals[d] = carry;
  }
  __syncthreads();

  if (t == 0) {
    int s = 0;
    #pragma unroll
    for (int d = 0; d < ND_; d++) { bases[d] = s; offsets[d] = s; s += totals[d]; }
    bases[ND_] = s; offsets[ND_] = s;
  }
  __syncthreads();

  #pragma unroll
  for (int i = 0; i < RPT; i++) {
    int d = yv[i];
    int pos = bases[d] + hist[d][t];
    hist[d][t]++;
    perm[pos] = base + i;
  }
}

// ---------------- GEMM ----------------
// C[M,N] = act(A[M,K] @ W[K,N] + bias) ; W pre-transposed f16 [N][Ktot].
// MODE 0: trunk; 1: expert first (gather A via perm); 2: expert mid; 3: expert last
// (scatter f32 out via perm, no relu, N=64 mask).
// Staging: global_load_lds 16B/lane into linear LDS [128][32] f16, DOUBLE-buffered:
// issue tile t+1's loads, compute tile t, single vmcnt(0)+barrier per K-step (T3 2-phase).
template<int MODE>
__global__ __launch_bounds__(256) void gemm_k(
    const f16* __restrict__ A, int lda,
    const f16* __restrict__ Wt, long w_dstride,
    const float* __restrict__ bias, int b_dstride,
    f16* __restrict__ out16, float* __restrict__ out32,
    const int* __restrict__ offsets, const int* __restrict__ perm,
    int Ktot)
{
  __shared__ f16 As[2][BM * BK];   // 2 x 8 KB
  __shared__ f16 Bs[2][BN * BK];   // 2 x 8 KB

  int n0 = blockIdx.x * BN;
  int moff, count;
  if (MODE >= 1) {
    int d = blockIdx.z;
    int o0 = offsets[d], o1 = offsets[d + 1];
    if ((int)blockIdx.y * BM >= (o1 - o0)) return;
    moff = o0 + blockIdx.y * BM;
    count = o1;  // absolute end of this domain's slot range
    Wt += (long)d * w_dstride;
    bias += d * b_dstride;
  } else {
    moff = blockIdx.y * BM;
    count = B_TOT;
  }

  int t = threadIdx.x;
  int lane = t & 63;
  int wid = t >> 6;                       // 4 waves: 2x2 of 64x64
  int wm = (wid >> 1) * 64, wn = (wid & 1) * 64;
  int lr = lane & 15, lg = lane >> 4;

  // staging geometry: chunk = 16B; thread t covers (row = t>>2, col = (t&3)*8);
  // wave-uniform LDS base + lane*16B lands exactly at linear offset t*8 f16.
  int rs = t >> 2;
  int cs = (t & 3) << 3;
  long arow0, arow1;
  {
    int s0 = moff + rs, s1 = moff + 64 + rs;
    if (MODE >= 1) {
      s0 = (s0 < count) ? s0 : count - 1;   // clamp: garbage rows discarded in epilogue
      s1 = (s1 < count) ? s1 : count - 1;
    }
    if (MODE == 1) { arow0 = perm[s0]; arow1 = perm[s1]; }
    else           { arow0 = s0;       arow1 = s1; }
  }
  const f16* ap0 = A + arow0 * lda + cs;
  const f16* ap1 = A + arow1 * lda + cs;
  const f16* wp0 = Wt + (long)(n0 + rs) * Ktot + cs;
  const f16* wp1 = Wt + (long)(n0 + 64 + rs) * Ktot + cs;
  int wb = wid * 512;                     // per-wave LDS block (f16 elems)

  f32x4 acc[4][4];
  #pragma unroll
  for (int m = 0; m < 4; m++)
    #pragma unroll
    for (int n = 0; n < 4; n++) acc[m][n] = f32x4{0.f, 0.f, 0.f, 0.f};

  #define STAGE(buf, kk) do {                         \
    gload16(ap0 + (kk), &As[buf][wb]);                \
    gload16(ap1 + (kk), &As[buf][2048 + wb]);         \
    gload16(wp0 + (kk), &Bs[buf][wb]);                \
    gload16(wp1 + (kk), &Bs[buf][2048 + wb]);         \
  } while (0)

  #define COMPUTE(buf) do {                                               \
    f16x8 af[4], bf[4];                                                   \
    _Pragma("unroll")                                                     \
    for (int m = 0; m < 4; m++)                                           \
      af[m] = *(const f16x8*)&As[buf][(wm + m * 16 + lr) * BK + lg * 8];  \
    _Pragma("unroll")                                                     \
    for (int n = 0; n < 4; n++)                                           \
      bf[n] = *(const f16x8*)&Bs[buf][(wn + n * 16 + lr) * BK + lg * 8];  \
    _Pragma("unroll")                                                     \
    for (int m = 0; m < 4; m++)                                           \
      _Pragma("unroll")                                                   \
      for (int n = 0; n < 4; n++)                                         \
        acc[m][n] = __builtin_amdgcn_mfma_f32_16x16x32_f16(af[m], bf[n], acc[m][n], 0, 0, 0); \
  } while (0)

  const int NT = Ktot / BK;
  STAGE(0, 0);
  asm volatile("s_waitcnt vmcnt(0)" ::: "memory");
  __builtin_amdgcn_s_barrier();
  int cur = 0;
  for (int ts = 0; ts < NT - 1; ts++) {
    STAGE(cur ^ 1, (ts + 1) * BK);        // issue next tile's loads (in flight)
    COMPUTE(cur);                          // ds_read + MFMA on current tile
    asm volatile("s_waitcnt vmcnt(0)" ::: "memory");
    __builtin_amdgcn_s_barrier();          // next buffer staged for all waves
    cur ^= 1;
  }
  COMPUTE(cur);                            // last tile, no prefetch

  #undef STAGE
  #undef COMPUTE

  // epilogue: C/D layout col = lane&15, row = (lane>>4)*4 + j
  float bcol[4];
  #pragma unroll
  for (int n = 0; n < 4; n++) {
    int cn = n0 + wn + n * 16 + lr;
    bcol[n] = (MODE == 3) ? ((cn < STY_) ? bias[cn] : 0.f) : bias[cn];
  }
  #pragma unroll
  for (int m = 0; m < 4; m++) {
    int rloc = wm + m * 16 + lg * 4;
    #pragma unroll
    for (int j = 0; j < 4; j++) {
      int r = moff + rloc + j;
      if (MODE >= 1 && r >= count) continue;
      #pragma unroll
      for (int n = 0; n < 4; n++) {
        int cn = n0 + wn + n * 16 + lr;
        float v = acc[m][n][j] + bcol[n];
        if (MODE == 3) {
          if (cn < STY_) out32[(long)perm[r] * STY_ + cn] = v;
        } else {
          out16[(long)r * HID_ + cn] = (f16)fmaxf(v, 0.f);
        }
      }
    }
  }
}

// ---------------- launch ----------------

extern "C" void kernel_launch(void* const* d_in, const int* in_sizes, int n_in,
                              void* d_out, int out_size, void* d_ws, size_t ws_size,
                              hipStream_t stream) {
  const float* x  = (const float*)d_in[0];
  const int*   y  = (const int*)  d_in[1];
  const float* W0 = (const float*)d_in[2];
  const float* b0 = (const float*)d_in[3];
  const float* W1 = (const float*)d_in[4];
  const float* b1 = (const float*)d_in[5];
  const float* W2 = (const float*)d_in[6];
  const float* b2 = (const float*)d_in[7];
  const float* W3 = (const float*)d_in[8];
  const float* b3 = (const float*)d_in[9];
  const float* U0 = (const float*)d_in[10];
  const float* c0 = (const float*)d_in[11];
  const float* U1 = (const float*)d_in[12];
  const float* c1 = (const float*)d_in[13];
  const float* U2 = (const float*)d_in[14];
  const float* c2 = (const float*)d_in[15];
  const float* U3 = (const float*)d_in[16];
  const float* c3 = (const float*)d_in[17];
  float* out = (float*)d_out;

  char* p = (char*)d_ws;
  auto alloc = [&](size_t bytes) -> char* {
    char* r = p; p += (bytes + 255) & ~(size_t)255; return r;
  };
  f16* x16 = (f16*)alloc((size_t)B_TOT * 32 * 2);
  f16* Wt0 = (f16*)alloc((size_t)512 * 32 * 2);
  f16* Wt1 = (f16*)alloc((size_t)512 * 512 * 2);
  f16* Wt2 = (f16*)alloc((size_t)512 * 512 * 2);
  f16* Wt3 = (f16*)alloc((size_t)512 * 512 * 2);
  f16* U0t = (f16*)alloc((size_t)ND_ * 512 * 512 * 2);
  f16* U1t = (f16*)alloc((size_t)ND_ * 512 * 512 * 2);
  f16* U2t = (f16*)alloc((size_t)ND_ * 512 * 512 * 2);
  f16* U3t = (f16*)alloc((size_t)ND_ * 128 * 512 * 2);  // N padded 64 -> 128
  f16* hA  = (f16*)alloc((size_t)B_TOT * HID_ * 2);
  f16* hB  = (f16*)alloc((size_t)B_TOT * HID_ * 2);
  int* offsets = (int*)alloc((ND_ + 1) * 4);
  int* perm    = (int*)alloc((size_t)B_TOT * 4);

  cast_x_k<<<(B_TOT * 32) / 256, 256, 0, stream>>>(x, x16);
  prep_k<<<dim3(16, 16, 36), dim3(32, 8), 0, stream>>>(W0, Wt0, W1, Wt1, W2, Wt2, W3, Wt3,
                                                       U0, U0t, U1, U1t, U2, U2t, U3, U3t);
  bucket_k<<<1, NT_BUCKET, 0, stream>>>(y, offsets, perm);

  // trunk: x16 -> hA -> hB -> hA -> hB
  gemm_k<0><<<dim3(4, 128, 1), 256, 0, stream>>>(x16, 32, Wt0, 0L, b0, 0, hA, nullptr, nullptr, nullptr, 32);
  gemm_k<0><<<dim3(4, 128, 1), 256, 0, stream>>>(hA, 512, Wt1, 0L, b1, 0, hB, nullptr, nullptr, nullptr, 512);
  gemm_k<0><<<dim3(4, 128, 1), 256, 0, stream>>>(hB, 512, Wt2, 0L, b2, 0, hA, nullptr, nullptr, nullptr, 512);
  gemm_k<0><<<dim3(4, 128, 1), 256, 0, stream>>>(hA, 512, Wt3, 0L, b3, 0, hB, nullptr, nullptr, nullptr, 512);
  // experts (grouped by domain): hB -(gather)-> hA -> hB -> hA -(scatter)-> out
  gemm_k<1><<<dim3(4, 128, ND_), 256, 0, stream>>>(hB, 512, U0t, (long)512 * 512, c0, 512, hA, nullptr, offsets, perm, 512);
  gemm_k<2><<<dim3(4, 128, ND_), 256, 0, stream>>>(hA, 512, U1t, (long)512 * 512, c1, 512, hB, nullptr, offsets, perm, 512);
  gemm_k<2><<<dim3(4, 128, ND_), 256, 0, stream>>>(hB, 512, U2t, (long)512 * 512, c2, 512, hA, nullptr, offsets, perm, 512);
  gemm_k<3><<<dim3(1, 128, ND_), 256, 0, stream>>>(hA, 512, U3t, (long)128 * 512, c3, 64, nullptr, out, offsets, perm, 512);
}